// Round 2
// 432.518 us; speedup vs baseline: 1.0075x; 1.0075x over previous
//
#include <hip/hip_runtime.h>

// G[u][x] = 0.5 * c_u * cos((2x+1)*u*pi/16),  c_0 = sqrt(0.5), c_u = 1 otherwise.
// scale[u,v]*h[u,x]*h[v,y] == G[u][x]*G[v][y]; the same table serves both
// separable IDCT passes. constexpr + literal indices -> folds to immediates.
__device__ constexpr float G[64] = {
    0.3535533906f,  0.3535533906f,  0.3535533906f,  0.3535533906f,
    0.3535533906f,  0.3535533906f,  0.3535533906f,  0.3535533906f,

    0.4903926402f,  0.4157348062f,  0.2777851165f,  0.0975451610f,
   -0.0975451610f, -0.2777851165f, -0.4157348062f, -0.4903926402f,

    0.4619397663f,  0.1913417162f, -0.1913417162f, -0.4619397663f,
   -0.4619397663f, -0.1913417162f,  0.1913417162f,  0.4619397663f,

    0.4157348062f, -0.0975451610f, -0.4903926402f, -0.2777851165f,
    0.2777851165f,  0.4903926402f,  0.0975451610f, -0.4157348062f,

    0.3535533906f, -0.3535533906f, -0.3535533906f,  0.3535533906f,
    0.3535533906f, -0.3535533906f, -0.3535533906f,  0.3535533906f,

    0.2777851165f, -0.4903926402f,  0.0975451610f,  0.4157348062f,
   -0.4157348062f, -0.0975451610f,  0.4903926402f, -0.2777851165f,

    0.1913417162f, -0.4619397663f,  0.4619397663f, -0.1913417162f,
   -0.1913417162f,  0.4619397663f, -0.4619397663f,  0.1913417162f,

    0.0975451610f, -0.2777851165f,  0.4157348062f, -0.4903926402f,
    0.4903926402f, -0.4157348062f,  0.2777851165f, -0.0975451610f,
};

#define WB 128  // 8x8 blocks (w positions) staged per workgroup

typedef __attribute__((address_space(1))) const void gvoid_t;
typedef __attribute__((address_space(3))) void lvoid_t;

// One workgroup stages a [64 channel][128 w] fp32 tile (32 KiB) for one (b,h)
// half-row via async global->LDS dwordx4, then 2 threads cooperate per 8x8
// block: thread xh=0 produces output rows 0..3, xh=1 rows 7..4 (cosine
// symmetry G[u][7-x] = (-1)^u G[u][x] keeps all table indices literal).
__global__ __launch_bounds__(256) void idct_kernel(
    const float* __restrict__ dct,
    const float* __restrict__ mean_,
    const float* __restrict__ std_,
    float* __restrict__ out)
{
    __shared__ __align__(16) float sh[64 * WB];  // sh[c*WB + w] = raw coeff

    const int t   = threadIdx.x;
    const int blk = blockIdx.x;          // 16 * 256 * 2 = 8192
    const int wh  = blk & 1;
    const int h   = (blk >> 1) & 255;
    const int b   = blk >> 9;
    const int w0  = wh * WB;

    // ---- stage: 64 ch x 128 w floats = 2048 float4, 8 iters x 256 threads.
    // Per wave: 2 channels x 512 B contiguous each; LDS dest is linear
    // (byte 16*idx = wave_base + lane*16), as global_load_lds requires.
    const float* gbase = dct + ((size_t)b << 22) + ((size_t)h << 8) + w0;
#pragma unroll
    for (int k = 0; k < 8; ++k) {
        const int idx = k * 256 + t;           // 0..2047
        const int c   = idx >> 5;              // channel 0..63
        const int wq  = idx & 31;              // float4 slot within row
        const float* gp = gbase + ((size_t)c << 16) + (wq << 2);
        __builtin_amdgcn_global_load_lds((gvoid_t*)gp,
                                         (lvoid_t*)(sh + (size_t)idx * 4),
                                         16, 0, 0);
    }
    __syncthreads();  // compiler drains vmcnt(0) before s_barrier

    // ---- compute: block j = t & 127, row-half xh = t >> 7 ----
    const int j  = t & (WB - 1);
    const int xh = t >> 7;
    const unsigned sgn = (unsigned)xh << 31;   // flips odd-u terms for xh=1

    float acc[4][8];
#pragma unroll
    for (int xi = 0; xi < 4; ++xi)
#pragma unroll
        for (int v = 0; v < 8; ++v) acc[xi][v] = 0.0f;

    // Pass 1 over u: acc[xi][v] = sum_u G[u][x] * (raw*std + mean),
    // x = xi (xh=0) or 7-xi (xh=1) via sign symmetry.
#pragma unroll
    for (int u = 0; u < 8; ++u) {
#pragma unroll
        for (int v = 0; v < 8; ++v) {
            const int c = u * 8 + v;
            const float raw = sh[c * WB + j];              // 2 lanes/bank: free
            const float dv  = fmaf(raw, std_[c], mean_[c]);
            const float dvs = __uint_as_float(__float_as_uint(dv) ^ sgn);
            const float dsel = (u & 1) ? dvs : dv;
#pragma unroll
            for (int xi = 0; xi < 4; ++xi)
                acc[xi][v] = fmaf(G[u * 8 + xi], dsel, acc[xi][v]);
        }
    }

    // Pass 2 over v + epilogue (pix+128)/255 folded into one FMA.
    const float inv255 = 1.0f / 255.0f;
    const float off128 = 128.0f / 255.0f;

    // out[b][0][8h+x][8*(w0+j) + y]
    const size_t orow0 = ((size_t)b << 22) + ((size_t)(h * 8) << 11)
                       + (size_t)((w0 + j) * 8);

#pragma unroll
    for (int xi = 0; xi < 4; ++xi) {
        const int x = xi ^ (xh * 7);           // xh=1 -> rows 7,6,5,4
        float pix[8];
#pragma unroll
        for (int y = 0; y < 8; ++y) {
            float s = 0.0f;
#pragma unroll
            for (int v = 0; v < 8; ++v)
                s = fmaf(G[v * 8 + y], acc[xi][v], s);
            pix[y] = fmaf(s, inv255, off128);
        }
        float4* o = (float4*)(out + orow0 + ((size_t)x << 11));
        o[0] = make_float4(pix[0], pix[1], pix[2], pix[3]);
        o[1] = make_float4(pix[4], pix[5], pix[6], pix[7]);
    }
}

extern "C" void kernel_launch(void* const* d_in, const int* in_sizes, int n_in,
                              void* d_out, int out_size, void* d_ws, size_t ws_size,
                              hipStream_t stream) {
    const float* dct  = (const float*)d_in[0];
    const float* mean = (const float*)d_in[1];
    const float* std_ = (const float*)d_in[2];
    float* out = (float*)d_out;

    // 16 b * 256 h * 2 w-halves = 8192 workgroups of 256 threads
    const int grid = 16 * 256 * 2;
    idct_kernel<<<grid, 256, 0, stream>>>(dct, mean, std_, out);
}